// Round 1
// baseline (669.289 us; speedup 1.0000x reference)
//
#include <hip/hip_runtime.h>
#include <hip/hip_bf16.h>
#include <cstdint>
#include <cstddef>

// WideLSTM: N=32 blocks, I=64, H=128, B=16, T=256.
// One workgroup per block n (512 threads = 8 waves). Weights held as
// persistent bf16 MFMA B-fragments in registers (24 frags = 96 VGPR/lane).
// Per step: gates[16,512] = [x_t | h_{t-1}] @ W^T via 16x16x32 bf16 MFMA
// (K=192), gate nonlinearities in C-layout regs, LDS exchange, c/h update.

#define TSTEPS 256
#define NBLK 32

typedef float  f32x4  __attribute__((ext_vector_type(4)));
typedef __bf16 bf16x8 __attribute__((ext_vector_type(8)));
typedef short  s16x8  __attribute__((ext_vector_type(8)));
typedef short  s16x4  __attribute__((ext_vector_type(4)));

union Frag {
  s16x8  s;
  bf16x8 b;
};

__device__ __forceinline__ short f2bf(float f) {
  // RNE float -> bf16 bit pattern
  uint32_t u = __builtin_bit_cast(uint32_t, f);
  u += 0x7fffu + ((u >> 16) & 1u);
  return (short)(u >> 16);
}

__device__ __forceinline__ float tanh_fast(float x) {
  // tanh(x) = 1 - 2/(1+e^{2x}); robust at +/-inf via exp2->inf->rcp->0
  return 1.f - 2.f * __builtin_amdgcn_rcpf(1.f + __builtin_amdgcn_exp2f(2.8853900817779268f * x));
}

__global__ __launch_bounds__(512, 2) void wide_lstm(
    const float* __restrict__ x,   const float* __restrict__ h0,
    const float* __restrict__ c0,  const float* __restrict__ wih,
    const float* __restrict__ whh, const float* __restrict__ bih,
    const float* __restrict__ bhh, float* __restrict__ out)
{
  const int n    = blockIdx.x;
  const int tid  = threadIdx.x;
  const int w    = tid >> 6;       // wave 0..7: owns gate cols [64w, 64w+64)
  const int lane = tid & 63;
  const int col  = lane & 15;      // MFMA col (gate) / A row (batch)
  const int quad = lane >> 4;      // 0..3

  // h_lds row stride 136 bf16 (=272B): 16B-aligned b128 reads, 2-way banks (free)
  __shared__ alignas(16) short h_lds[16 * 136];
  // gact row stride 132 f32: breaks 128-stride bank aliasing
  __shared__ alignas(16) float gact[4 * 16 * 132];
  __shared__ alignas(16) float c_lds[16 * 128];

  // ---- one-time: load weights into persistent bf16 B-fragments ----
  // B[k][g]: k<64 -> Wih[n][g][k], k>=64 -> Whh[n][g][k-64]
  // frag layout: lane holds B[k0+quad*8+jj][64w+16j+col], jj=0..7
  Frag  bfr[6][4];
  float bias_s[4];
  int   cidx[4];
#pragma unroll
  for (int j = 0; j < 4; ++j) {
    const int g = 64 * w + 16 * j + col;
    bias_s[j] = bih[n * 512 + g] + bhh[n * 512 + g];
    cidx[j]   = g & 127;
#pragma unroll
    for (int s = 0; s < 6; ++s) {
      const int k0 = 32 * s + quad * 8;
      const float* p = (s < 2) ? (wih + ((size_t)(n * 512 + g)) * 64  + k0)
                               : (whh + ((size_t)(n * 512 + g)) * 128 + (k0 - 64));
      const f32x4 lo = *(const f32x4*)p;
      const f32x4 hi = *(const f32x4*)(p + 4);
      Frag f;
      f.s[0] = f2bf(lo[0]); f.s[1] = f2bf(lo[1]); f.s[2] = f2bf(lo[2]); f.s[3] = f2bf(lo[3]);
      f.s[4] = f2bf(hi[0]); f.s[5] = f2bf(hi[1]); f.s[6] = f2bf(hi[2]); f.s[7] = f2bf(hi[3]);
      bfr[s][j] = f;
    }
  }

  // ---- init state from h0/c0 ----
  {
    const int b  = tid >> 5;
    const int j0 = (tid & 31) * 4;
    const f32x4 hv = *(const f32x4*)(h0 + (size_t)b * 4096 + n * 128 + j0);
    const f32x4 cv = *(const f32x4*)(c0 + (size_t)b * 4096 + n * 128 + j0);
    *(f32x4*)&c_lds[b * 128 + j0] = cv;
    s16x4 hs;
    hs[0] = f2bf(hv[0]); hs[1] = f2bf(hv[1]); hs[2] = f2bf(hv[2]); hs[3] = f2bf(hv[3]);
    *(s16x4*)&h_lds[b * 136 + j0] = hs;
  }
  __syncthreads();

  // wave-uniform activation constants: act(x) = ka * rcp(1 + exp2(kk*x)) + kb
  // sigmoid: 1*rcp(1+exp2(-x/ln2)) + 0 ; tanh: -2*rcp(1+exp2(2x/ln2)) + 1
  const int   is_tanh = ((w >> 1) == 2);
  const float kk = is_tanh ?  2.8853900817779268f : -1.4426950408889634f;
  const float ka = is_tanh ? -2.f : 1.f;
  const float kb = is_tanh ?  1.f : 0.f;
  const int   tbase = (w >> 1) * (16 * 132);

  const float* xp = x + (size_t)col * (TSTEPS * 2048) + n * 64 + quad * 8;
  const int db = tid >> 5;
  const int dj = (tid & 31) * 4;
  float* outp = out + (size_t)db * (TSTEPS * 4096) + n * 128 + dj;

  for (int t = 0; t < TSTEPS; ++t) {
    // ---- A fragments: k 0..63 from x_t (global), k 64..191 from h_lds ----
    Frag a[6];
    {
      const f32x4 l0 = *(const f32x4*)(xp);
      const f32x4 m0 = *(const f32x4*)(xp + 4);
      const f32x4 l1 = *(const f32x4*)(xp + 32);
      const f32x4 m1 = *(const f32x4*)(xp + 36);
      a[0].s[0] = f2bf(l0[0]); a[0].s[1] = f2bf(l0[1]); a[0].s[2] = f2bf(l0[2]); a[0].s[3] = f2bf(l0[3]);
      a[0].s[4] = f2bf(m0[0]); a[0].s[5] = f2bf(m0[1]); a[0].s[6] = f2bf(m0[2]); a[0].s[7] = f2bf(m0[3]);
      a[1].s[0] = f2bf(l1[0]); a[1].s[1] = f2bf(l1[1]); a[1].s[2] = f2bf(l1[2]); a[1].s[3] = f2bf(l1[3]);
      a[1].s[4] = f2bf(m1[0]); a[1].s[5] = f2bf(m1[1]); a[1].s[6] = f2bf(m1[2]); a[1].s[7] = f2bf(m1[3]);
    }
#pragma unroll
    for (int s = 2; s < 6; ++s)
      a[s].s = *(const s16x8*)&h_lds[col * 136 + 32 * (s - 2) + quad * 8];

    // ---- MFMA: D[16,512] over K=192, 24 mfma/wave ----
    f32x4 acc[4];
#pragma unroll
    for (int j = 0; j < 4; ++j) acc[j] = (f32x4){0.f, 0.f, 0.f, 0.f};
#pragma unroll
    for (int s = 0; s < 6; ++s)
#pragma unroll
      for (int j = 0; j < 4; ++j)
        acc[j] = __builtin_amdgcn_mfma_f32_16x16x32_bf16(a[s].b, bfr[s][j].b, acc[j], 0, 0, 0);

    // ---- epilogue: bias + activation in C-layout, scatter to gact ----
    // C layout: row(batch) = quad*4 + r, col(gate) = 64w + 16j + col
#pragma unroll
    for (int j = 0; j < 4; ++j) {
#pragma unroll
      for (int r = 0; r < 4; ++r) {
        const float pre = acc[j][r] + bias_s[j];
        const float av  = ka * __builtin_amdgcn_rcpf(1.f + __builtin_amdgcn_exp2f(kk * pre)) + kb;
        gact[tbase + (quad * 4 + r) * 132 + cidx[j]] = av;
      }
    }
    __syncthreads();

    // ---- state update: 512 threads x 4 h-elements ----
    const f32x4 ig = *(const f32x4*)&gact[0 * 2112 + db * 132 + dj];
    const f32x4 fg = *(const f32x4*)&gact[1 * 2112 + db * 132 + dj];
    const f32x4 gg = *(const f32x4*)&gact[2 * 2112 + db * 132 + dj];
    const f32x4 og = *(const f32x4*)&gact[3 * 2112 + db * 132 + dj];
    f32x4 cv = *(const f32x4*)&c_lds[db * 128 + dj];
    f32x4 cn, hn;
#pragma unroll
    for (int e = 0; e < 4; ++e) {
      cn[e] = fg[e] * cv[e] + ig[e] * gg[e];
      hn[e] = og[e] * tanh_fast(cn[e]);
    }
    *(f32x4*)&c_lds[db * 128 + dj] = cn;
    s16x4 hs;
#pragma unroll
    for (int e = 0; e < 4; ++e) hs[e] = f2bf(hn[e]);
    *(s16x4*)&h_lds[db * 136 + dj] = hs;
    *(f32x4*)outp = hn;                       // output[b][t][n*128+j]
    if (t == TSTEPS - 1) {
      *(f32x4*)(out + 16777216 + (size_t)db * 4096 + n * 128 + dj) = hn;          // h_n
      *(f32x4*)(out + 16777216 + 65536 + (size_t)db * 4096 + n * 128 + dj) = cn;  // c_n
    }
    __syncthreads();

    xp   += 2048;
    outp += 4096;
  }
}

extern "C" void kernel_launch(void* const* d_in, const int* in_sizes, int n_in,
                              void* d_out, int out_size, void* d_ws, size_t ws_size,
                              hipStream_t stream) {
  const float* x   = (const float*)d_in[0];
  const float* h0  = (const float*)d_in[1];
  const float* c0  = (const float*)d_in[2];
  const float* wih = (const float*)d_in[3];
  const float* whh = (const float*)d_in[4];
  const float* bih = (const float*)d_in[5];
  const float* bhh = (const float*)d_in[6];
  float* out = (float*)d_out;
  wide_lstm<<<NBLK, 512, 0, stream>>>(x, h0, c0, wih, whh, bih, bhh, out);
}

// Round 2
// 516.012 us; speedup vs baseline: 1.2970x; 1.2970x over previous
//
#include <hip/hip_runtime.h>
#include <hip/hip_bf16.h>
#include <cstdint>
#include <cstddef>

// WideLSTM: N=32 blocks, I=64, H=128, B=16, T=256.
// One workgroup per block n (512 thr = 8 waves). Weights persistent as bf16
// MFMA B-fragments (24 frags = 96 VGPR/lane). Wave w owns h-indices
// [16w,16w+16); frag j = gate TYPE (i,f,g,o) -> each thread holds all four
// gate values for its (batch,h) in registers, c-state register-resident,
// ONE barrier/step (double-buffered h_lds), CK-style lgkm-only barrier so
// global x loads / out stores never drain at the barrier.

#define TSTEPS 256
#define NBLK 32

typedef float  f32x4  __attribute__((ext_vector_type(4)));
typedef __bf16 bf16x8 __attribute__((ext_vector_type(8)));
typedef short  s16x8  __attribute__((ext_vector_type(8)));
typedef short  s16x4  __attribute__((ext_vector_type(4)));

union Frag { s16x8 s; bf16x8 b; };

__device__ __forceinline__ short f2bf(float f) {
  // RNE float -> bf16 bit pattern
  uint32_t u = __builtin_bit_cast(uint32_t, f);
  u += 0x7fffu + ((u >> 16) & 1u);
  return (short)(u >> 16);
}

__device__ __forceinline__ void cvt8(Frag& d, f32x4 lo, f32x4 hi) {
  d.s[0]=f2bf(lo[0]); d.s[1]=f2bf(lo[1]); d.s[2]=f2bf(lo[2]); d.s[3]=f2bf(lo[3]);
  d.s[4]=f2bf(hi[0]); d.s[5]=f2bf(hi[1]); d.s[6]=f2bf(hi[2]); d.s[7]=f2bf(hi[3]);
}

// composable_kernel block_sync_lds: wait LDS only, NO vmcnt drain.
__device__ __forceinline__ void sync_lds() {
  asm volatile("s_waitcnt lgkmcnt(0)" ::: "memory");
  __builtin_amdgcn_s_barrier();
  asm volatile("" ::: "memory");
}

__device__ __forceinline__ float sigm_f(float pre) {
  // sigmoid(pre) = rcp(1 + exp2(-pre/ln2)); exact at +/-inf via inf->rcp->0
  return __builtin_amdgcn_rcpf(1.f + __builtin_amdgcn_exp2f(-1.4426950408889634f * pre));
}
__device__ __forceinline__ float tanh_f(float pre) {
  // tanh(pre) = 1 - 2*rcp(1 + exp2(2*pre/ln2))
  return 1.f - 2.f * __builtin_amdgcn_rcpf(1.f + __builtin_amdgcn_exp2f(2.8853900817779268f * pre));
}

__global__ __launch_bounds__(512, 2) void wide_lstm(
    const float* __restrict__ x,   const float* __restrict__ h0,
    const float* __restrict__ c0,  const float* __restrict__ wih,
    const float* __restrict__ whh, const float* __restrict__ bih,
    const float* __restrict__ bhh, float* __restrict__ out)
{
  const int n    = blockIdx.x;
  const int tid  = threadIdx.x;
  const int w    = tid >> 6;       // wave 0..7: owns h-indices [16w,16w+16)
  const int lane = tid & 63;
  const int col  = lane & 15;      // A row (batch) / B col (h-within-16)
  const int quad = lane >> 4;      // 0..3 (k-chunk for A/B; C row group)
  const int hb   = 16 * w + col;   // this lane's h index

  // double-buffered h (bf16), row stride 136 shorts (272B)
  __shared__ alignas(16) short h_lds[2][16 * 136];

  // ---- one-time: weights -> persistent bf16 B-fragments ----
  // frag j = gate type; gate col g = 128*j + 16*w + col
  // lane holds B[k=32s+quad*8+jj][g], k<64 -> Wih, k>=64 -> Whh
  Frag  bfr[6][4];
  float bias_s[4];
#pragma unroll
  for (int j = 0; j < 4; ++j) {
    const int g = 128 * j + 16 * w + col;
    bias_s[j] = bih[n * 512 + g] + bhh[n * 512 + g];
#pragma unroll
    for (int s = 0; s < 6; ++s) {
      const int k0 = 32 * s + quad * 8;
      const float* p = (s < 2) ? (wih + (size_t)(n * 512 + g) * 64  + k0)
                               : (whh + (size_t)(n * 512 + g) * 128 + (k0 - 64));
      cvt8(bfr[s][j], *(const f32x4*)p, *(const f32x4*)(p + 4));
    }
  }

  // ---- init state ----
  {
    const int b = tid >> 5, j0 = (tid & 31) * 4;
    const f32x4 hv = *(const f32x4*)(h0 + (size_t)b * 4096 + n * 128 + j0);
    s16x4 hs;
    hs[0]=f2bf(hv[0]); hs[1]=f2bf(hv[1]); hs[2]=f2bf(hv[2]); hs[3]=f2bf(hv[3]);
    *(s16x4*)&h_lds[0][b * 136 + j0] = hs;
  }
  float creg[4];                    // c[b=quad*4+r][hb], register-resident
#pragma unroll
  for (int r = 0; r < 4; ++r)
    creg[r] = c0[(size_t)(quad * 4 + r) * 4096 + n * 128 + hb];
  __syncthreads();                  // full barrier once (init)

  // x prefetch: A rows = batch = col, k = quad*8 within 64
  const float* xp = x + (size_t)col * (TSTEPS * 2048) + n * 64 + quad * 8;
  f32x4 xr0 = *(const f32x4*)xp,        xr1 = *(const f32x4*)(xp + 4);
  f32x4 xr2 = *(const f32x4*)(xp + 32), xr3 = *(const f32x4*)(xp + 36);

  float* ob = out + (size_t)(quad * 4) * (TSTEPS * 4096) + n * 128 + hb;

  int cur = 0;
  for (int t = 0; t < TSTEPS; ++t) {
    // ---- A fragments: k 0..63 from prefetched x, k 64..191 from h_lds ----
    Frag a[6];
    cvt8(a[0], xr0, xr1);
    cvt8(a[1], xr2, xr3);
#pragma unroll
    for (int s = 0; s < 4; ++s)
      a[2 + s].s = *(const s16x8*)&h_lds[cur][col * 136 + 32 * s + quad * 8];

    // prefetch x for t+1 (stays in flight across the barrier: no vmcnt drain)
    if (t + 1 < TSTEPS) {
      xp += 2048;
      xr0 = *(const f32x4*)xp;        xr1 = *(const f32x4*)(xp + 4);
      xr2 = *(const f32x4*)(xp + 32); xr3 = *(const f32x4*)(xp + 36);
    }

    // ---- MFMA: 24/wave, acc[j] = gate type j for (batch=quad*4+r, h=hb) ----
    f32x4 acc[4];
#pragma unroll
    for (int j = 0; j < 4; ++j) acc[j] = (f32x4){0.f, 0.f, 0.f, 0.f};
#pragma unroll
    for (int s = 0; s < 6; ++s)
#pragma unroll
      for (int j = 0; j < 4; ++j)
        acc[j] = __builtin_amdgcn_mfma_f32_16x16x32_bf16(a[s].b, bfr[s][j].b, acc[j], 0, 0, 0);

    // ---- gates + state update entirely in registers ----
    const int nxt = cur ^ 1;
    float hnv[4];
#pragma unroll
    for (int r = 0; r < 4; ++r) {
      const float ig = sigm_f(acc[0][r] + bias_s[0]);
      const float fg = sigm_f(acc[1][r] + bias_s[1]);
      const float gg = tanh_f(acc[2][r] + bias_s[2]);
      const float og = sigm_f(acc[3][r] + bias_s[3]);
      const float cn = fg * creg[r] + ig * gg;
      creg[r] = cn;
      hnv[r]  = og * tanh_f(cn);
    }

    // h -> other LDS buffer (bf16), scattered b16 x4
#pragma unroll
    for (int r = 0; r < 4; ++r)
      h_lds[nxt][(quad * 4 + r) * 136 + hb] = f2bf(hnv[r]);

    // output store (async; never drained at barrier)
#pragma unroll
    for (int r = 0; r < 4; ++r)
      ob[(size_t)r * (TSTEPS * 4096) + (size_t)t * 4096] = hnv[r];
    if (t == TSTEPS - 1) {
#pragma unroll
      for (int r = 0; r < 4; ++r) {
        out[16777216 +         (size_t)(quad * 4 + r) * 4096 + n * 128 + hb] = hnv[r];   // h_n
        out[16777216 + 65536 + (size_t)(quad * 4 + r) * 4096 + n * 128 + hb] = creg[r];  // c_n
      }
    }

    sync_lds();   // lgkmcnt(0) + s_barrier, NO vmcnt drain
    cur = nxt;
  }
}

extern "C" void kernel_launch(void* const* d_in, const int* in_sizes, int n_in,
                              void* d_out, int out_size, void* d_ws, size_t ws_size,
                              hipStream_t stream) {
  const float* x   = (const float*)d_in[0];
  const float* h0  = (const float*)d_in[1];
  const float* c0  = (const float*)d_in[2];
  const float* wih = (const float*)d_in[3];
  const float* whh = (const float*)d_in[4];
  const float* bih = (const float*)d_in[5];
  const float* bhh = (const float*)d_in[6];
  float* out = (float*)d_out;
  wide_lstm<<<NBLK, 512, 0, stream>>>(x, h0, c0, wih, whh, bih, bhh, out);
}

// Round 3
// 341.678 us; speedup vs baseline: 1.9588x; 1.5102x over previous
//
#include <hip/hip_runtime.h>
#include <hip/hip_bf16.h>
#include <cstdint>
#include <cstddef>

// WideLSTM: N=32 blocks, I=64, H=128, B=16, T=256.
// One WG per block n (512 thr = 8 waves). TRANSPOSED mfma mapping:
//   D[gate, batch] = W[gate,k] (A operand, persistent regs) x [x|h][k,batch] (B).
// Lane owns 4 CONSECUTIVE h for ONE batch -> b64 h-write, dwordx4 out-store,
// register-resident c. x staged via LDS as bf16 (converted once per WG, not
// once per wave), distance-2 global prefetch. One lgkm-only barrier per step.

#define TSTEPS 256
#define NBLK 32

typedef float  f32x4  __attribute__((ext_vector_type(4)));
typedef float  f32x2  __attribute__((ext_vector_type(2)));
typedef __bf16 bf16x8 __attribute__((ext_vector_type(8)));
typedef short  s16x8  __attribute__((ext_vector_type(8)));
typedef short  s16x4  __attribute__((ext_vector_type(4)));

union Frag { s16x8 s; bf16x8 b; };

#define KSIG -1.4426950408889634f   // -1/ln2 (sigmoid)
#define KTAN  2.8853900817779268f   //  2/ln2 (tanh)

__device__ __forceinline__ short f2bf(float f) {
  uint32_t u = __builtin_bit_cast(uint32_t, f);
  u += 0x7fffu + ((u >> 16) & 1u);
  return (short)(u >> 16);
}

// lgkm-only barrier: global loads/stores stay in flight across it
__device__ __forceinline__ void sync_lds() {
  asm volatile("s_waitcnt lgkmcnt(0)" ::: "memory");
  __builtin_amdgcn_s_barrier();
  asm volatile("" ::: "memory");
}

__global__ __launch_bounds__(512, 2) void wide_lstm(
    const float* __restrict__ x,   const float* __restrict__ h0,
    const float* __restrict__ c0,  const float* __restrict__ wih,
    const float* __restrict__ whh, const float* __restrict__ bih,
    const float* __restrict__ bhh, float* __restrict__ out)
{
  const int n    = blockIdx.x;
  const int tid  = threadIdx.x;
  const int w    = tid >> 6;       // wave 0..7
  const int lane = tid & 63;
  const int col  = lane & 15;      // batch (B-operand col / D col)
  const int quad = lane >> 4;      // k-chunk for A/B; D row group
  const int hq   = 16 * w + quad * 4;   // first of 4 consecutive h this lane owns

  // [batch][h] bf16, double-buffered; stride 136 shorts (272 B, 16-aligned)
  __shared__ alignas(16) short h_lds[2][16 * 136];
  // [batch][k] bf16 x-tile, double-buffered; stride 72 shorts (144 B)
  __shared__ alignas(16) short x_lds[2][16 * 72];

  // ---- weights -> persistent A-fragments ----
  // A tile j (gate type): lane holds W[g = 128j + 16w + col][k = 32s + quad*8 + jj]
  Frag wfr[6][4];
#pragma unroll
  for (int j = 0; j < 4; ++j) {
    const int g = 128 * j + 16 * w + col;
#pragma unroll
    for (int s = 0; s < 6; ++s) {
      const int k0 = 32 * s + quad * 8;
      const float* p = (s < 2) ? (wih + (size_t)(n * 512 + g) * 64  + k0)
                               : (whh + (size_t)(n * 512 + g) * 128 + (k0 - 64));
      const f32x4 lo = *(const f32x4*)p;
      const f32x4 hi = *(const f32x4*)(p + 4);
      Frag f;
      f.s[0]=f2bf(lo[0]); f.s[1]=f2bf(lo[1]); f.s[2]=f2bf(lo[2]); f.s[3]=f2bf(lo[3]);
      f.s[4]=f2bf(hi[0]); f.s[5]=f2bf(hi[1]); f.s[6]=f2bf(hi[2]); f.s[7]=f2bf(hi[3]);
      wfr[s][j] = f;
    }
  }

  // ---- bias with activation scale folded in: z = fma(acc, k, kb) ----
  f32x4 kb[4];
#pragma unroll
  for (int j = 0; j < 4; ++j) {
    const int base = n * 512 + 128 * j + 16 * w + quad * 4;
    const f32x4 b1 = *(const f32x4*)(bih + base);
    const f32x4 b2 = *(const f32x4*)(bhh + base);
    const float k  = (j == 2) ? KTAN : KSIG;
#pragma unroll
    for (int r = 0; r < 4; ++r) kb[j][r] = k * (b1[r] + b2[r]);
  }

  // ---- init state + x(0) staging ----
  {
    const int b = tid >> 5, j0 = (tid & 31) * 4;
    const f32x4 hv = *(const f32x4*)(h0 + (size_t)b * 4096 + n * 128 + j0);
    s16x4 hs;
    hs[0]=f2bf(hv[0]); hs[1]=f2bf(hv[1]); hs[2]=f2bf(hv[2]); hs[3]=f2bf(hv[3]);
    *(s16x4*)&h_lds[0][b * 136 + j0] = hs;
  }
  const int bx = tid >> 5;
  const int kx = (tid & 31) * 2;
  const float* xbase = x + (size_t)bx * (TSTEPS * 2048) + n * 64 + kx;
  {
    const f32x2 x0 = *(const f32x2*)xbase;
    uint32_t pk = (uint16_t)f2bf(x0[0]) | ((uint32_t)(uint16_t)f2bf(x0[1]) << 16);
    *(uint32_t*)&x_lds[0][bx * 72 + kx] = pk;
  }
  f32x4 creg = *(const f32x4*)(c0 + (size_t)col * 4096 + n * 128 + hq);
  __syncthreads();

  f32x2 xr = *(const f32x2*)(xbase + 2048);   // x(1)
  const float* xnext = xbase + 2 * 2048;      // x(t+2) load cursor

  float* outp = out + (size_t)col * (TSTEPS * 4096) + n * 128 + hq;
  f32x4 ho;

  int cur = 0;
  for (int t = 0; t < TSTEPS; ++t) {
    const int nxt = cur ^ 1;

    // ---- B fragments: k 0..63 from x_lds, k 64..191 from h_lds ----
    Frag bfrag[6];
    bfrag[0].s = *(const s16x8*)&x_lds[cur][col * 72 + quad * 8];
    bfrag[1].s = *(const s16x8*)&x_lds[cur][col * 72 + 32 + quad * 8];
#pragma unroll
    for (int s = 0; s < 4; ++s)
      bfrag[2 + s].s = *(const s16x8*)&h_lds[cur][col * 136 + 32 * s + quad * 8];

    // stage x(t+1) into other buffer (reg was loaded a full step ago)
    {
      uint32_t pk = (uint16_t)f2bf(xr[0]) | ((uint32_t)(uint16_t)f2bf(xr[1]) << 16);
      *(uint32_t*)&x_lds[nxt][bx * 72 + kx] = pk;
    }
    if (t < TSTEPS - 2) { xr = *(const f32x2*)xnext; xnext += 2048; }

    // ---- MFMA: A = weights, B = [x|h]; D[gate-in-tile, batch] ----
    f32x4 acc[4];
#pragma unroll
    for (int j = 0; j < 4; ++j) acc[j] = (f32x4){0.f, 0.f, 0.f, 0.f};
#pragma unroll
    for (int s = 0; s < 6; ++s)
#pragma unroll
      for (int j = 0; j < 4; ++j)
        acc[j] = __builtin_amdgcn_mfma_f32_16x16x32_bf16(wfr[s][j].b, bfrag[s].b, acc[j], 0, 0, 0);

    // ---- gates + state, all in registers (lane: batch=col, h=hq..hq+3) ----
#pragma unroll
    for (int r = 0; r < 4; ++r) {
      const float si = __builtin_amdgcn_rcpf(1.f + __builtin_amdgcn_exp2f(__builtin_fmaf(acc[0][r], KSIG, kb[0][r])));
      const float sf = __builtin_amdgcn_rcpf(1.f + __builtin_amdgcn_exp2f(__builtin_fmaf(acc[1][r], KSIG, kb[1][r])));
      const float sg = __builtin_amdgcn_rcpf(1.f + __builtin_amdgcn_exp2f(__builtin_fmaf(acc[2][r], KTAN, kb[2][r])));
      const float so = __builtin_amdgcn_rcpf(1.f + __builtin_amdgcn_exp2f(__builtin_fmaf(acc[3][r], KSIG, kb[3][r])));
      // cn = sf*c + si*(1-2sg) = fma(-2, si*sg, fma(sf, c, si))
      float cn = __builtin_fmaf(sf, creg[r], si);
      cn = __builtin_fmaf(-2.f, si * sg, cn);
      creg[r] = cn;
      const float rc = __builtin_amdgcn_rcpf(1.f + __builtin_amdgcn_exp2f(KTAN * cn));
      ho[r] = so * __builtin_fmaf(-2.f, rc, 1.f);   // o * tanh(cn)
    }

    // h -> other buffer: 4 consecutive bf16 = one b64 write
    s16x4 hs;
#pragma unroll
    for (int r = 0; r < 4; ++r) hs[r] = f2bf(ho[r]);
    *(s16x4*)&h_lds[nxt][col * 136 + hq] = hs;

    // out[b=col][t][n*128 + hq..hq+3] : one dwordx4, fire-and-forget
    *(f32x4*)outp = ho;
    outp += 4096;

    sync_lds();
    cur = nxt;
  }

  // ---- h_n / c_n ----
  *(f32x4*)(out + 16777216 +         (size_t)col * 4096 + n * 128 + hq) = ho;
  *(f32x4*)(out + 16777216 + 65536 + (size_t)col * 4096 + n * 128 + hq) = creg;
}

extern "C" void kernel_launch(void* const* d_in, const int* in_sizes, int n_in,
                              void* d_out, int out_size, void* d_ws, size_t ws_size,
                              hipStream_t stream) {
  const float* x   = (const float*)d_in[0];
  const float* h0  = (const float*)d_in[1];
  const float* c0  = (const float*)d_in[2];
  const float* wih = (const float*)d_in[3];
  const float* whh = (const float*)d_in[4];
  const float* bih = (const float*)d_in[5];
  const float* bhh = (const float*)d_in[6];
  float* out = (float*)d_out;
  wide_lstm<<<NBLK, 512, 0, stream>>>(x, h0, c0, wih, whh, bih, bhh, out);
}